// Round 2
// baseline (369.272 us; speedup 1.0000x reference)
//
#include <hip/hip_runtime.h>

#define MOD 242

static constexpr long long OFF_STATE = 1;
static constexpr long long OFF_SA    = 18433;
static constexpr long long OFF_SG    = 4478977;
static constexpr long long OFF_OG    = 4495361;
static constexpr long long OFF_GRAD  = 8955905;
static constexpr long long OFF_OWG   = 42510337;

// ws layout (floats). Partials are deterministic (no atomics, no memset needed).
#define WS_HID  0            // [32 iblk][2048 w][8 d]  hidden partials (2 MB)
#define WS_CON  524288       // [16 wblk][2048 i][8 d]  contrib partials (1 MB)
#define WS_COL  786432       // [2048][8] sg*relu_g
#define WS_ROW  802816       // [2048][8] act_prev
#define WS_OUTP 819200       // [128] per-block output partials (finalize grid = 128)

// ---- DPP wave-64 sum (VALU pipe only, no LDS). Result valid in lane 63. ----
template <int CTRL, int RM>
__device__ __forceinline__ float dppadd(float x) {
  int t = __builtin_amdgcn_update_dpp(0, __float_as_int(x), CTRL, RM, 0xF, true);
  return x + __int_as_float(t);
}
__device__ __forceinline__ float wave_sum_dpp(float x) {
  x = dppadd<0x111, 0xF>(x);   // row_shr:1
  x = dppadd<0x112, 0xF>(x);   // row_shr:2
  x = dppadd<0x114, 0xF>(x);   // row_shr:4
  x = dppadd<0x118, 0xF>(x);   // row_shr:8  -> lane15 of each row = row sum
  x = dppadd<0x142, 0xA>(x);   // row_bcast:15 into rows 1,3
  x = dppadd<0x143, 0xC>(x);   // row_bcast:31 into rows 2,3 -> lane63 = total
  return x;
}

// Fused single pass over weights (134 MB read once):
//   hidden[w,d]  = sum_i weights[i,w,d] * state[i,d]   (registers -> partial store)
//   contrib[i,d] = sum_w weights[i,w,d] * sgrad[w,d]   (DPP wave reduction)
// Lane layout: lane l = w offset (64 consecutive w per wave); wave = (wgrp, dhalf).
// NOTE (R1 post-mortem): do NOT append the sa/og bulk copy here — at 512 blocks
// the copy phase is latency-limited (~2.8 TB/s) and serializes after the
// weights pass; it belongs in a high-occupancy streaming kernel (k_grad).
__global__ __launch_bounds__(256) void k_matvec(
    const float* __restrict__ weights, const float* __restrict__ state,
    const float* __restrict__ sgrad, float* __restrict__ ws)
{
  const int b    = blockIdx.x;
  const int iblk = b & 31;
  const int wblk = b >> 5;
  const int i0   = iblk * 64;
  const int w0   = wblk * 128;
  const int tid  = threadIdx.x;
  const int wv   = tid >> 6;
  const int l    = tid & 63;
  const int wgrp = wv >> 1;          // which 64-w group
  const int dh   = wv & 1;           // which float4 half of d
  const int w    = w0 + wgrp * 64 + l;

  __shared__ __align__(16) float state_lds[64 * 8];
  __shared__ __align__(16) float cl[4][64][4];   // per-wave contrib partials

  for (int idx = tid; idx < 64 * 8; idx += 256)
    state_lds[idx] = state[(size_t)(i0 + (idx >> 3)) * 9 + (idx & 7)];
  __syncthreads();

  const float4 sg4 = *(const float4*)&sgrad[(size_t)w * 8 + dh * 4];
  float4 h4 = make_float4(0.f, 0.f, 0.f, 0.f);
  const float* wp = weights + ((size_t)i0 * 2048 + w) * 8 + dh * 4;

  #pragma unroll 4
  for (int ii = 0; ii < 64; ++ii) {
    const float4 w4 = *(const float4*)wp;
    wp += 16384;                                        // next i row
    const float4 s4 = *(const float4*)&state_lds[ii * 8 + dh * 4]; // broadcast

    h4.x = fmaf(w4.x, s4.x, h4.x);
    h4.y = fmaf(w4.y, s4.y, h4.y);
    h4.z = fmaf(w4.z, s4.z, h4.z);
    h4.w = fmaf(w4.w, s4.w, h4.w);

    float vx = wave_sum_dpp(w4.x * sg4.x);
    float vy = wave_sum_dpp(w4.y * sg4.y);
    float vz = wave_sum_dpp(w4.z * sg4.z);
    float vw = wave_sum_dpp(w4.w * sg4.w);
    if (l == 63)
      *(float4*)&cl[wv][ii][0] = make_float4(vx, vy, vz, vw);
  }

  // hidden partial: [iblk][w][d], each lane owns (w, dhalf)
  *(float4*)&ws[WS_HID + ((size_t)iblk * 2048 + w) * 8 + dh * 4] = h4;

  __syncthreads();
  // contrib partial: combine the two w-groups; [wblk][i][d]
  {
    const int ii = tid >> 2, q = tid & 3;
    const float c0 = cl[0][ii][q] + cl[2][ii][q];   // d = q
    const float c1 = cl[1][ii][q] + cl[3][ii][q];   // d = q + 4
    const size_t base = WS_CON + ((size_t)wblk * 2048 + i0 + ii) * 8;
    ws[base + q]     = c0;
    ws[base + 4 + q] = c1;
  }
}

// Per-row epilogue: reduce partials, state/owg/output/sg, sa/og time column,
// colfac/rowfac staging. Grid 128 x 64: 4-lane team per row (4x the load
// parallelism and 4x the CUs of the old 32x64 config; it was latency-bound).
__global__ __launch_bounds__(64) void k_finalize(
    const float* __restrict__ x, const float* __restrict__ ow,
    const float* __restrict__ sa_in, const float* __restrict__ og_in,
    const int* __restrict__ timep, float* __restrict__ ws, float* __restrict__ out)
{
  const int tid = threadIdx.x;
  const int q   = tid & 3;                 // team lane
  const int r   = blockIdx.x * 16 + (tid >> 2);
  const int t   = *timep;

  float hid[8] = {0,0,0,0,0,0,0,0};
  {
    const float4* hp = (const float4*)&ws[WS_HID + (size_t)r * 8];
    #pragma unroll
    for (int k = 0; k < 8; ++k) {
      const size_t ib = (size_t)(q + 4 * k);
      const float4 pa = hp[ib * 4096];
      const float4 pb = hp[ib * 4096 + 1];
      hid[0] += pa.x; hid[1] += pa.y; hid[2] += pa.z; hid[3] += pa.w;
      hid[4] += pb.x; hid[5] += pb.y; hid[6] += pb.z; hid[7] += pb.w;
    }
  }
  float con[8] = {0,0,0,0,0,0,0,0};
  {
    const float4* cp = (const float4*)&ws[WS_CON + (size_t)r * 8];
    #pragma unroll
    for (int k = 0; k < 4; ++k) {
      const size_t wb = (size_t)(q + 4 * k);
      const float4 pa = cp[wb * 4096];
      const float4 pb = cp[wb * 4096 + 1];
      con[0] += pa.x; con[1] += pa.y; con[2] += pa.z; con[3] += pa.w;
      con[4] += pb.x; con[5] += pb.y; con[6] += pb.z; con[7] += pb.w;
    }
  }
  // combine the 4-lane team (teams are lane-aligned groups of 4)
  #pragma unroll
  for (int m = 1; m <= 2; m <<= 1) {
    #pragma unroll
    for (int d = 0; d < 8; ++d) {
      hid[d] += __shfl_xor(hid[d], m);
      con[d] += __shfl_xor(con[d], m);
    }
  }

  float p = 0.f;
  if (q == 0) {
    float s[9];
    s[0] = x[r];
    #pragma unroll
    for (int d = 0; d < 8; ++d) s[d + 1] = fmaxf(hid[d], 0.f);

    float owr[9];
    #pragma unroll
    for (int c = 0; c < 9; ++c) owr[c] = ow[(size_t)r * 9 + c];

    #pragma unroll
    for (int c = 0; c < 9; ++c) {
      out[OFF_STATE + (size_t)r * 9 + c] = s[c];
      out[OFF_OWG   + (size_t)r * 9 + c] = s[c];
      out[OFF_SA + ((size_t)r * 9 + c) * MOD + t] = s[c];
      out[OFF_OG + ((size_t)r * 9 + c) * MOD + t] = owr[c];
      p = fmaf(owr[c], s[c], p);
    }

    float sg[8];
    #pragma unroll
    for (int a = 0; a < 7; ++a) {
      const int ti = (t + 2 * a - 14 + MOD) % MOD;
      const int tm = (ti + 1) % MOD;
      const float av  = (tm == t) ? s[a + 2] : sa_in[((size_t)r * 9 + a + 2) * MOD + tm];
      const float ogv = (ti == t) ? owr[a + 1] : og_in[((size_t)r * 9 + a + 1) * MOD + ti];
      sg[a] = (av > 0.f ? con[a + 1] : 0.f) + ogv;
    }
    sg[7] = owr[8];
    #pragma unroll
    for (int a = 0; a < 8; ++a) out[OFF_SG + (size_t)r * 8 + a] = sg[a];

    #pragma unroll
    for (int aa = 0; aa < 8; ++aa) {
      const int ti = (t + 2 * aa - 14 + MOD) % MOD;
      const int tp = (ti - 1 + MOD) % MOD;
      const float rv = (ti == t) ? s[aa + 1] : sa_in[((size_t)r * 9 + aa + 1) * MOD + ti];
      const float ap = (tp == t) ? s[aa]     : sa_in[((size_t)r * 9 + aa) * MOD + tp];
      ws[WS_COL + r * 8 + aa] = (rv > 0.f) ? sg[aa] : 0.f;
      ws[WS_ROW + r * 8 + aa] = ap;
    }
  }
  // block output partial: 16 rows/block, p nonzero only on q==0 lanes
  #pragma unroll
  for (int m = 1; m < 64; m <<= 1) p += __shfl_xor(p, m);
  if (tid == 0) ws[WS_OUTP + blockIdx.x] = p;
}

// gradients[i,j,a] = rowfac[i,a] * colfac[j,a]; 134 MB coalesced write.
// OFF_GRAD == 1 (mod 4) -> element e == 3 (mod 4) is 16B-aligned: peel 3 head
// + 1 tail elements, dwordx4-store the remaining 16380 per row.
// Also: (a) finishes the output scalar (partials from k_finalize);
// (b) carries the sa/og bulk copy — block i copies exactly row i's
//     [9][242] slice (2178 = 9*242 elems each), SKIPPING time column t,
//     which k_finalize already wrote (this kernel runs after finalize).
//     High occupancy here (2048 blocks) keeps the copy at full HBM BW.
__global__ __launch_bounds__(256) void k_grad(
    const float* __restrict__ ws, const float* __restrict__ sa_in,
    const float* __restrict__ og_in, const int* __restrict__ timep,
    float* __restrict__ out)
{
  const int i = blockIdx.x;
  const int tid = threadIdx.x;
  const int t = *timep;
  if (i == 0 && tid == 0) {
    float s = 0.f;
    #pragma unroll
    for (int k = 0; k < 128; ++k) s += ws[WS_OUTP + k];
    out[0] = s;
  }

  // ---- bulk copy slice (row i of sa/og), skip column t ----
  {
    const int e0 = i * 2178;
    for (int e = tid; e < 2178; e += 256) {
      const int c  = e / 242;           // magic-mul by compiler
      const int tm = e - c * 242;
      const float va = sa_in[e0 + e];
      const float vb = og_in[e0 + e];
      if (tm != t) {
        out[OFF_SA + (size_t)(e0 + e)] = va;
        out[OFF_OG + (size_t)(e0 + e)] = vb;
      }
    }
  }

  // ---- gradients row i ----
  const float4* rp = (const float4*)&ws[WS_ROW + (size_t)i * 8];
  const float4 rA = rp[0];   // rf[0..3]
  const float4 rB = rp[1];   // rf[4..7]
  // e0 = 4v+3; v parity == tid parity (stride 256): even -> a = {3,4,5,6},
  // odd -> a = {7,0,1,2} (a only depends on e mod 8; rf has no j dependence).
  const float4 rf4 = (tid & 1)
      ? make_float4(rB.w, rA.x, rA.y, rA.z)
      : make_float4(rA.w, rB.x, rB.y, rB.z);
  const float* cf = ws + WS_COL;
  float* o = out + OFF_GRAD + (size_t)i * 16384;

  #pragma unroll 4
  for (int v = tid; v < 4095; v += 256) {
    const int e0 = 4 * v + 3;
    const float c0 = cf[e0], c1 = cf[e0 + 1], c2 = cf[e0 + 2], c3 = cf[e0 + 3];
    *(float4*)&o[e0] = make_float4(rf4.x * c0, rf4.y * c1, rf4.z * c2, rf4.w * c3);
  }
  if (tid == 0) o[0] = rA.x * cf[0];
  if (tid == 1) o[1] = rA.y * cf[1];
  if (tid == 2) o[2] = rA.z * cf[2];
  if (tid == 3) o[16383] = rB.w * cf[16383];   // a = 7
}

extern "C" void kernel_launch(void* const* d_in, const int* in_sizes, int n_in,
                              void* d_out, int out_size, void* d_ws, size_t ws_size,
                              hipStream_t stream)
{
  (void)in_sizes; (void)n_in; (void)out_size; (void)ws_size;
  const float* x     = (const float*)d_in[0];
  const float* wts   = (const float*)d_in[1];
  const float* ow    = (const float*)d_in[2];
  const float* st    = (const float*)d_in[3];
  const float* sa_in = (const float*)d_in[4];
  const float* sgrad = (const float*)d_in[5];
  const float* og_in = (const float*)d_in[6];
  const int*   timep = (const int*)d_in[7];
  float* out = (float*)d_out;
  float* ws  = (float*)d_ws;

  k_matvec<<<512, 256, 0, stream>>>(wts, st, sgrad, ws);
  k_finalize<<<128, 64, 0, stream>>>(x, ow, sa_in, og_in, timep, ws, out);
  k_grad<<<2048, 256, 0, stream>>>(ws, sa_in, og_in, timep, out);
}

// Round 3
// 335.990 us; speedup vs baseline: 1.0991x; 1.0991x over previous
//
#include <hip/hip_runtime.h>

#define MOD 242

static constexpr long long OFF_STATE = 1;
static constexpr long long OFF_SA    = 18433;
static constexpr long long OFF_SG    = 4478977;
static constexpr long long OFF_OG    = 4495361;
static constexpr long long OFF_GRAD  = 8955905;
static constexpr long long OFF_OWG   = 42510337;

// ws layout (floats). Partials are deterministic (no atomics, no memset needed).
#define WS_HID  0            // [32 iblk][2048 w][8 d]  hidden partials (2 MB)
#define WS_CON  524288       // [16 wblk][2048 i][8 d]  contrib partials (1 MB)
#define WS_COL  786432       // [2048][8] sg*relu_g
#define WS_ROW  802816       // [2048][8] act_prev
#define WS_OUTP 819200       // [32] per-block output partials

// ---- DPP wave-64 sum (VALU pipe only, no LDS). Result valid in lane 63. ----
template <int CTRL, int RM>
__device__ __forceinline__ float dppadd(float x) {
  int t = __builtin_amdgcn_update_dpp(0, __float_as_int(x), CTRL, RM, 0xF, true);
  return x + __int_as_float(t);
}
__device__ __forceinline__ float wave_sum_dpp(float x) {
  x = dppadd<0x111, 0xF>(x);   // row_shr:1
  x = dppadd<0x112, 0xF>(x);   // row_shr:2
  x = dppadd<0x114, 0xF>(x);   // row_shr:4
  x = dppadd<0x118, 0xF>(x);   // row_shr:8  -> lane15 of each row = row sum
  x = dppadd<0x142, 0xA>(x);   // row_bcast:15 into rows 1,3
  x = dppadd<0x143, 0xC>(x);   // row_bcast:31 into rows 2,3 -> lane63 = total
  return x;
}

// Heterogeneous-grid kernel (R3): one launch, two block roles.
//   blocks 0..511    : fused weights pass, byte-identical to the proven R0 body
//   blocks 512..4863 : sa/og bulk copy at full parallelism (grid-stride)
// R1/R2 lesson: fusing the copy as a sequential PHASE inside matvec/grad
// blocks regressed ~+22us (serialized at low per-phase occupancy). Here the
// copy runs in its OWN blocks, co-resident with the memory-stalled matvec
// blocks (only 2/CU), so its traffic overlaps instead of following.
__global__ __launch_bounds__(256) void k_mvcopy(
    const float* __restrict__ weights, const float* __restrict__ state,
    const float* __restrict__ sgrad, const float* __restrict__ sa_in,
    const float* __restrict__ og_in, float* __restrict__ ws,
    float* __restrict__ out)
{
  const int b   = blockIdx.x;
  const int tid = threadIdx.x;

  if (b >= 512) {
    // ---- copy role: 4352 blocks x 256 threads, 4-5 elems each ----
    const unsigned g = (unsigned)(b - 512) * 256u + (unsigned)tid;
    for (size_t e = g; e < 4460544u; e += 1114112u) {
      out[OFF_SA + e] = sa_in[e];
      out[OFF_OG + e] = og_in[e];
    }
    return;
  }

  // ---- matvec role (exactly the R0 body) ----
  const int iblk = b & 31;
  const int wblk = b >> 5;
  const int i0   = iblk * 64;
  const int w0   = wblk * 128;
  const int wv   = tid >> 6;
  const int l    = tid & 63;
  const int wgrp = wv >> 1;          // which 64-w group
  const int dh   = wv & 1;           // which float4 half of d
  const int w    = w0 + wgrp * 64 + l;

  __shared__ __align__(16) float state_lds[64 * 8];
  __shared__ __align__(16) float cl[4][64][4];   // per-wave contrib partials

  for (int idx = tid; idx < 64 * 8; idx += 256)
    state_lds[idx] = state[(size_t)(i0 + (idx >> 3)) * 9 + (idx & 7)];
  __syncthreads();

  const float4 sg4 = *(const float4*)&sgrad[(size_t)w * 8 + dh * 4];
  float4 h4 = make_float4(0.f, 0.f, 0.f, 0.f);
  const float* wp = weights + ((size_t)i0 * 2048 + w) * 8 + dh * 4;

  #pragma unroll 4
  for (int ii = 0; ii < 64; ++ii) {
    const float4 w4 = *(const float4*)wp;
    wp += 16384;                                        // next i row
    const float4 s4 = *(const float4*)&state_lds[ii * 8 + dh * 4]; // broadcast

    h4.x = fmaf(w4.x, s4.x, h4.x);
    h4.y = fmaf(w4.y, s4.y, h4.y);
    h4.z = fmaf(w4.z, s4.z, h4.z);
    h4.w = fmaf(w4.w, s4.w, h4.w);

    float vx = wave_sum_dpp(w4.x * sg4.x);
    float vy = wave_sum_dpp(w4.y * sg4.y);
    float vz = wave_sum_dpp(w4.z * sg4.z);
    float vw = wave_sum_dpp(w4.w * sg4.w);
    if (l == 63)
      *(float4*)&cl[wv][ii][0] = make_float4(vx, vy, vz, vw);
  }

  // hidden partial: [iblk][w][d], each lane owns (w, dhalf)
  *(float4*)&ws[WS_HID + ((size_t)iblk * 2048 + w) * 8 + dh * 4] = h4;

  __syncthreads();
  // contrib partial: combine the two w-groups; [wblk][i][d]
  {
    const int ii = tid >> 2, q = tid & 3;
    const float c0 = cl[0][ii][q] + cl[2][ii][q];   // d = q
    const float c1 = cl[1][ii][q] + cl[3][ii][q];   // d = q + 4
    const size_t base = WS_CON + ((size_t)wblk * 2048 + i0 + ii) * 8;
    ws[base + q]     = c0;
    ws[base + 4 + q] = c1;
  }
}

// Per-row epilogue: reduce partials, state/owg/output/sg, sa/og time column,
// colfac/rowfac staging. Grid 32 x 64 (one wave per block) — exact R0 version.
__global__ __launch_bounds__(64) void k_finalize(
    const float* __restrict__ x, const float* __restrict__ ow,
    const float* __restrict__ sa_in, const float* __restrict__ og_in,
    const int* __restrict__ timep, float* __restrict__ ws, float* __restrict__ out)
{
  const int r = blockIdx.x * 64 + threadIdx.x;
  const int t = *timep;

  float hid[8] = {0,0,0,0,0,0,0,0};
  {
    const float4* hp = (const float4*)&ws[WS_HID + (size_t)r * 8];
    #pragma unroll
    for (int ib = 0; ib < 32; ++ib) {
      const float4 pa = hp[(size_t)ib * 4096];
      const float4 pb = hp[(size_t)ib * 4096 + 1];
      hid[0] += pa.x; hid[1] += pa.y; hid[2] += pa.z; hid[3] += pa.w;
      hid[4] += pb.x; hid[5] += pb.y; hid[6] += pb.z; hid[7] += pb.w;
    }
  }
  float con[8] = {0,0,0,0,0,0,0,0};
  {
    const float4* cp = (const float4*)&ws[WS_CON + (size_t)r * 8];
    #pragma unroll
    for (int wb = 0; wb < 16; ++wb) {
      const float4 pa = cp[(size_t)wb * 4096];
      const float4 pb = cp[(size_t)wb * 4096 + 1];
      con[0] += pa.x; con[1] += pa.y; con[2] += pa.z; con[3] += pa.w;
      con[4] += pb.x; con[5] += pb.y; con[6] += pb.z; con[7] += pb.w;
    }
  }

  float s[9];
  s[0] = x[r];
  #pragma unroll
  for (int d = 0; d < 8; ++d) s[d + 1] = fmaxf(hid[d], 0.f);

  float owr[9];
  #pragma unroll
  for (int c = 0; c < 9; ++c) owr[c] = ow[(size_t)r * 9 + c];

  float p = 0.f;
  #pragma unroll
  for (int c = 0; c < 9; ++c) {
    out[OFF_STATE + (size_t)r * 9 + c] = s[c];
    out[OFF_OWG   + (size_t)r * 9 + c] = s[c];
    out[OFF_SA + ((size_t)r * 9 + c) * MOD + t] = s[c];
    out[OFF_OG + ((size_t)r * 9 + c) * MOD + t] = owr[c];
    p = fmaf(owr[c], s[c], p);
  }
  #pragma unroll
  for (int m = 1; m < 64; m <<= 1) p += __shfl_xor(p, m);
  if (threadIdx.x == 0) ws[WS_OUTP + blockIdx.x] = p;

  float sg[8];
  #pragma unroll
  for (int a = 0; a < 7; ++a) {
    const int ti = (t + 2 * a - 14 + MOD) % MOD;
    const int tm = (ti + 1) % MOD;
    const float av  = (tm == t) ? s[a + 2] : sa_in[((size_t)r * 9 + a + 2) * MOD + tm];
    const float ogv = (ti == t) ? owr[a + 1] : og_in[((size_t)r * 9 + a + 1) * MOD + ti];
    sg[a] = (av > 0.f ? con[a + 1] : 0.f) + ogv;
  }
  sg[7] = owr[8];
  #pragma unroll
  for (int a = 0; a < 8; ++a) out[OFF_SG + (size_t)r * 8 + a] = sg[a];

  #pragma unroll
  for (int aa = 0; aa < 8; ++aa) {
    const int ti = (t + 2 * aa - 14 + MOD) % MOD;
    const int tp = (ti - 1 + MOD) % MOD;
    const float rv = (ti == t) ? s[aa + 1] : sa_in[((size_t)r * 9 + aa + 1) * MOD + ti];
    const float ap = (tp == t) ? s[aa]     : sa_in[((size_t)r * 9 + aa) * MOD + tp];
    ws[WS_COL + r * 8 + aa] = (rv > 0.f) ? sg[aa] : 0.f;
    ws[WS_ROW + r * 8 + aa] = ap;
  }
}

// gradients[i,j,a] = rowfac[i,a] * colfac[j,a]; 134 MB coalesced write.
// Exact R0 version (scalar stores already exceed the HBM write drain rate).
// Also finishes the output scalar (partials written by k_finalize).
__global__ __launch_bounds__(256) void k_grad(
    const float* __restrict__ ws, float* __restrict__ out)
{
  const int i = blockIdx.x;
  const int tid = threadIdx.x;
  if (i == 0 && tid == 0) {
    float s = 0.f;
    #pragma unroll
    for (int k = 0; k < 32; ++k) s += ws[WS_OUTP + k];
    out[0] = s;
  }
  const float rf = ws[WS_ROW + i * 8 + (tid & 7)];
  float* o = out + OFF_GRAD + (size_t)i * 16384;
  const float* cf = ws + WS_COL;
  #pragma unroll 4
  for (int k = 0; k < 64; ++k) {
    const int e = k * 256 + tid;
    o[e] = rf * cf[e];
  }
}

extern "C" void kernel_launch(void* const* d_in, const int* in_sizes, int n_in,
                              void* d_out, int out_size, void* d_ws, size_t ws_size,
                              hipStream_t stream)
{
  (void)in_sizes; (void)n_in; (void)out_size; (void)ws_size;
  const float* x     = (const float*)d_in[0];
  const float* wts   = (const float*)d_in[1];
  const float* ow    = (const float*)d_in[2];
  const float* st    = (const float*)d_in[3];
  const float* sa_in = (const float*)d_in[4];
  const float* sgrad = (const float*)d_in[5];
  const float* og_in = (const float*)d_in[6];
  const int*   timep = (const int*)d_in[7];
  float* out = (float*)d_out;
  float* ws  = (float*)d_ws;

  k_mvcopy<<<4864, 256, 0, stream>>>(wts, st, sgrad, sa_in, og_in, ws, out);
  k_finalize<<<32, 64, 0, stream>>>(x, ow, sa_in, og_in, timep, ws, out);
  k_grad<<<2048, 256, 0, stream>>>(ws, out);
}

// Round 4
// 334.753 us; speedup vs baseline: 1.1031x; 1.0037x over previous
//
#include <hip/hip_runtime.h>

#define MOD 242

static constexpr long long OFF_STATE = 1;
static constexpr long long OFF_SA    = 18433;
static constexpr long long OFF_SG    = 4478977;
static constexpr long long OFF_OG    = 4495361;
static constexpr long long OFF_GRAD  = 8955905;
static constexpr long long OFF_OWG   = 42510337;

// ws layout (floats). Partials are deterministic (no atomics, no memset needed).
#define WS_HID  0            // [32 iblk][2048 w][8 d]  hidden partials (2 MB)
#define WS_CON  524288       // [16 wblk][2048 i][8 d]  contrib partials (1 MB)
#define WS_COL  786432       // [2048][8] sg*relu_g
#define WS_ROW  802816       // [2048][8] act_prev
#define WS_OUTP 819200       // [2048] per-row output partials (finalize grid = 2048)

// ---- DPP wave-64 sum (VALU pipe only, no LDS). Result valid in lane 63. ----
template <int CTRL, int RM>
__device__ __forceinline__ float dppadd(float x) {
  int t = __builtin_amdgcn_update_dpp(0, __float_as_int(x), CTRL, RM, 0xF, true);
  return x + __int_as_float(t);
}
__device__ __forceinline__ float wave_sum_dpp(float x) {
  x = dppadd<0x111, 0xF>(x);   // row_shr:1
  x = dppadd<0x112, 0xF>(x);   // row_shr:2
  x = dppadd<0x114, 0xF>(x);   // row_shr:4
  x = dppadd<0x118, 0xF>(x);   // row_shr:8  -> lane15 of each row = row sum
  x = dppadd<0x142, 0xA>(x);   // row_bcast:15 into rows 1,3
  x = dppadd<0x143, 0xC>(x);   // row_bcast:31 into rows 2,3 -> lane63 = total
  return x;
}

// Heterogeneous-grid kernel (R3, unchanged): one launch, two block roles.
//   blocks 0..511    : fused weights pass (R0 body)
//   blocks 512..4863 : sa/og bulk copy at full parallelism
// R1/R2 lesson: fusing the copy as a sequential PHASE regressed ~+22us;
// co-resident copy BLOCKS overlap the traffic instead (-7us, R3).
__global__ __launch_bounds__(256) void k_mvcopy(
    const float* __restrict__ weights, const float* __restrict__ state,
    const float* __restrict__ sgrad, const float* __restrict__ sa_in,
    const float* __restrict__ og_in, float* __restrict__ ws,
    float* __restrict__ out)
{
  const int b   = blockIdx.x;
  const int tid = threadIdx.x;

  if (b >= 512) {
    const unsigned g = (unsigned)(b - 512) * 256u + (unsigned)tid;
    for (size_t e = g; e < 4460544u; e += 1114112u) {
      out[OFF_SA + e] = sa_in[e];
      out[OFF_OG + e] = og_in[e];
    }
    return;
  }

  const int iblk = b & 31;
  const int wblk = b >> 5;
  const int i0   = iblk * 64;
  const int w0   = wblk * 128;
  const int wv   = tid >> 6;
  const int l    = tid & 63;
  const int wgrp = wv >> 1;          // which 64-w group
  const int dh   = wv & 1;           // which float4 half of d
  const int w    = w0 + wgrp * 64 + l;

  __shared__ __align__(16) float state_lds[64 * 8];
  __shared__ __align__(16) float cl[4][64][4];   // per-wave contrib partials

  for (int idx = tid; idx < 64 * 8; idx += 256)
    state_lds[idx] = state[(size_t)(i0 + (idx >> 3)) * 9 + (idx & 7)];
  __syncthreads();

  const float4 sg4 = *(const float4*)&sgrad[(size_t)w * 8 + dh * 4];
  float4 h4 = make_float4(0.f, 0.f, 0.f, 0.f);
  const float* wp = weights + ((size_t)i0 * 2048 + w) * 8 + dh * 4;

  #pragma unroll 4
  for (int ii = 0; ii < 64; ++ii) {
    const float4 w4 = *(const float4*)wp;
    wp += 16384;                                        // next i row
    const float4 s4 = *(const float4*)&state_lds[ii * 8 + dh * 4]; // broadcast

    h4.x = fmaf(w4.x, s4.x, h4.x);
    h4.y = fmaf(w4.y, s4.y, h4.y);
    h4.z = fmaf(w4.z, s4.z, h4.z);
    h4.w = fmaf(w4.w, s4.w, h4.w);

    float vx = wave_sum_dpp(w4.x * sg4.x);
    float vy = wave_sum_dpp(w4.y * sg4.y);
    float vz = wave_sum_dpp(w4.z * sg4.z);
    float vw = wave_sum_dpp(w4.w * sg4.w);
    if (l == 63)
      *(float4*)&cl[wv][ii][0] = make_float4(vx, vy, vz, vw);
  }

  *(float4*)&ws[WS_HID + ((size_t)iblk * 2048 + w) * 8 + dh * 4] = h4;

  __syncthreads();
  {
    const int ii = tid >> 2, q = tid & 3;
    const float c0 = cl[0][ii][q] + cl[2][ii][q];   // d = q
    const float c1 = cl[1][ii][q] + cl[3][ii][q];   // d = q + 4
    const size_t base = WS_CON + ((size_t)wblk * 2048 + i0 + ii) * 8;
    ws[base + q]     = c0;
    ws[base + 4 + q] = c1;
  }
}

// Per-row epilogue, ONE ROW PER BLOCK (2048 blocks x 256 threads).
// R0 ran 32 blocks x 64 threads = 2048 threads chip-wide (latency-bound,
// 224 CUs idle). Here a 256-lane team reduces the 32 hid + 16 con partials
// via shuffles and the scattered per-row tail is spread across lanes.
__global__ __launch_bounds__(256) void k_finalize(
    const float* __restrict__ x, const float* __restrict__ ow,
    const float* __restrict__ sa_in, const float* __restrict__ og_in,
    const int* __restrict__ timep, float* __restrict__ ws, float* __restrict__ out)
{
  const int r   = blockIdx.x;
  const int tid = threadIdx.x;
  const int wv  = tid >> 6;
  const int l   = tid & 63;
  const int t   = *timep;

  __shared__ float hred[4][8];
  __shared__ float cred[2][8];
  __shared__ float s_sh[9];
  __shared__ float owr_sh[9];

  // hid partials: tid -> (iblk = tid>>3, d = tid&7); wave wv covers iblk 8wv..8wv+7
  float hv = ws[WS_HID + ((size_t)(tid >> 3) * 2048 + r) * 8 + (tid & 7)];
  hv += __shfl_xor(hv, 8);
  hv += __shfl_xor(hv, 16);
  hv += __shfl_xor(hv, 32);
  if (l < 8) hred[wv][l] = hv;        // lane d holds wave partial for d

  // con partials: tids 0..127 -> (wblk = tid>>3, d = tid&7)
  float cv = 0.f;
  if (tid < 128) cv = ws[WS_CON + ((size_t)(tid >> 3) * 2048 + r) * 8 + (tid & 7)];
  cv += __shfl_xor(cv, 8);
  cv += __shfl_xor(cv, 16);
  cv += __shfl_xor(cv, 32);
  if (wv < 2 && l < 8) cred[wv][l] = cv;

  if (tid < 8 + 8)  { /* no-op spacer to keep branches simple */ }
  if (tid >= 16 && tid < 25) owr_sh[tid - 16] = ow[(size_t)r * 9 + (tid - 16)];
  if (tid == 8) s_sh[0] = x[r];
  __syncthreads();

  if (tid < 8) s_sh[tid + 1] = fmaxf(hred[0][tid] + hred[1][tid] + hred[2][tid] + hred[3][tid], 0.f);
  __syncthreads();

  // c-loop: 9 lanes store the 4 per-column outputs
  if (tid < 9) {
    const int c = tid;
    const float sc = s_sh[c], owc = owr_sh[c];
    out[OFF_STATE + (size_t)r * 9 + c] = sc;
    out[OFF_OWG   + (size_t)r * 9 + c] = sc;
    out[OFF_SA + ((size_t)r * 9 + c) * MOD + t] = sc;
    out[OFF_OG + ((size_t)r * 9 + c) * MOD + t] = owc;
  }
  // output partial for this row: 9-term dot, reduced over lanes 0..15
  {
    float pterm = (tid < 9) ? s_sh[tid] * owr_sh[tid] : 0.f;
    if (wv == 0) {
      pterm += __shfl_xor(pterm, 1);
      pterm += __shfl_xor(pterm, 2);
      pterm += __shfl_xor(pterm, 4);
      pterm += __shfl_xor(pterm, 8);
      if (l == 0) ws[WS_OUTP + r] = pterm;
    }
  }

  // sg + col/row factors: lane a handles index a (sg stays in-register)
  if (tid < 8) {
    const int a = tid;
    float sg;
    if (a < 7) {
      const int ti = (t + 2 * a - 14 + MOD) % MOD;
      const int tm = (ti + 1) % MOD;
      const float av  = (tm == t) ? s_sh[a + 2] : sa_in[((size_t)r * 9 + a + 2) * MOD + tm];
      const float ogv = (ti == t) ? owr_sh[a + 1] : og_in[((size_t)r * 9 + a + 1) * MOD + ti];
      const float con_a1 = cred[0][a + 1] + cred[1][a + 1];
      sg = (av > 0.f ? con_a1 : 0.f) + ogv;
    } else {
      sg = owr_sh[8];
    }
    out[OFF_SG + (size_t)r * 8 + a] = sg;

    const int ti = (t + 2 * a - 14 + MOD) % MOD;
    const int tp = (ti - 1 + MOD) % MOD;
    const float rv = (ti == t) ? s_sh[a + 1] : sa_in[((size_t)r * 9 + a + 1) * MOD + ti];
    const float ap = (tp == t) ? s_sh[a]     : sa_in[((size_t)r * 9 + a) * MOD + tp];
    ws[WS_COL + r * 8 + a] = (rv > 0.f) ? sg : 0.f;
    ws[WS_ROW + r * 8 + a] = ap;
  }
}

// gradients[i,j,a] = rowfac[i,a] * colfac[j,a]; 134 MB coalesced write.
// Store loop identical to R0/R3 (scalar stores already exceed HBM write
// drain rate). Output-scalar reduction parallelized for 2048 partials
// (block-uniform branch -> internal __syncthreads is safe).
__global__ __launch_bounds__(256) void k_grad(
    const float* __restrict__ ws, float* __restrict__ out)
{
  const int i = blockIdx.x;
  const int tid = threadIdx.x;
  if (i == 0) {
    float s = 0.f;
    #pragma unroll
    for (int k = 0; k < 8; ++k) s += ws[WS_OUTP + k * 256 + tid];
    #pragma unroll
    for (int m = 1; m < 64; m <<= 1) s += __shfl_xor(s, m);
    __shared__ float wsum[4];
    if ((tid & 63) == 0) wsum[tid >> 6] = s;
    __syncthreads();
    if (tid == 0) out[0] = wsum[0] + wsum[1] + wsum[2] + wsum[3];
  }
  const float rf = ws[WS_ROW + i * 8 + (tid & 7)];
  float* o = out + OFF_GRAD + (size_t)i * 16384;
  const float* cf = ws + WS_COL;
  #pragma unroll 4
  for (int k = 0; k < 64; ++k) {
    const int e = k * 256 + tid;
    o[e] = rf * cf[e];
  }
}

extern "C" void kernel_launch(void* const* d_in, const int* in_sizes, int n_in,
                              void* d_out, int out_size, void* d_ws, size_t ws_size,
                              hipStream_t stream)
{
  (void)in_sizes; (void)n_in; (void)out_size; (void)ws_size;
  const float* x     = (const float*)d_in[0];
  const float* wts   = (const float*)d_in[1];
  const float* ow    = (const float*)d_in[2];
  const float* st    = (const float*)d_in[3];
  const float* sa_in = (const float*)d_in[4];
  const float* sgrad = (const float*)d_in[5];
  const float* og_in = (const float*)d_in[6];
  const int*   timep = (const int*)d_in[7];
  float* out = (float*)d_out;
  float* ws  = (float*)d_ws;

  k_mvcopy<<<4864, 256, 0, stream>>>(wts, st, sgrad, sa_in, og_in, ws, out);
  k_finalize<<<2048, 256, 0, stream>>>(x, ow, sa_in, og_in, timep, ws, out);
  k_grad<<<2048, 256, 0, stream>>>(ws, out);
}